// Round 11
// baseline (757.689 us; speedup 1.0000x reference)
//
#include <hip/hip_runtime.h>

#define N_NODES 50000
#define N_EDGES 1600000
#define D 128
#define NCHUNK 196            // ceil(N_NODES/256) for scans
#define NBL 16384             // nodes per hist/fill block (64KB LDS)
#define NODEBLKS 4            // ceil(N_NODES/NBL)
#define NPAD 65536            // NODEBLKS*NBL
#define NSEG 128
#define CHUNKS_PER_SEG 3125   // uint4 chunks per segment (E/4/NSEG)

typedef _Float16 f16x8 __attribute__((ext_vector_type(8)));
typedef float f32x4 __attribute__((ext_vector_type(4)));
typedef uint u32x4 __attribute__((ext_vector_type(4)));   // ext-vector: valid for nontemporal builtins

union HU { uint4 u; u32x4 v; _Float16 h[8]; };

// ---------------- preprocessing: node-range-owning scan (NO global atomics) ----------------

__global__ __launch_bounds__(1024) void histA_kernel(const int* __restrict__ col, ushort* __restrict__ C){
  __shared__ uint cnt[NBL];
  const int nb = blockIdx.x, s = blockIdx.y;
  const uint n0 = nb*NBL;
  const int t = threadIdx.x;
  #pragma unroll
  for (int k=0;k<NBL/1024;k++) cnt[k*1024 + t] = 0;
  __syncthreads();
  const uint4* cv = (const uint4*)col;
  const int cb = s*CHUNKS_PER_SEG, ce = cb + CHUNKS_PER_SEG;
  for (int c = cb + t; c < ce; c += 1024){
    uint4 v = cv[c];
    unsigned d0 = v.x - n0, d1 = v.y - n0, d2 = v.z - n0, d3 = v.w - n0;
    if (d0 < NBL) atomicAdd(&cnt[d0], 1u);
    if (d1 < NBL) atomicAdd(&cnt[d1], 1u);
    if (d2 < NBL) atomicAdd(&cnt[d2], 1u);
    if (d3 < NBL) atomicAdd(&cnt[d3], 1u);
  }
  __syncthreads();
  #pragma unroll
  for (int k=0;k<NBL/1024;k++)
    C[(size_t)s*NPAD + n0 + k*1024 + t] = (ushort)cnt[k*1024 + t];
}

// In-place exclusive prefix of C along segments; deg, dinv, rdeg=sqrt(deg); fused chunk sums.
__global__ __launch_bounds__(256) void segprefix_kernel(ushort* __restrict__ C, int* __restrict__ deg,
                                                        float* __restrict__ dinv, float* __restrict__ rdeg,
                                                        int* __restrict__ chunkSum){
  __shared__ int red[256];
  int t = threadIdx.x;
  int n = blockIdx.x*256 + t;
  uint run = 0;
  if (n < N_NODES){
    #pragma unroll
    for (int s=0;s<NSEG;s++){
      uint v = C[(size_t)s*NPAD + n];
      C[(size_t)s*NPAD + n] = (ushort)run;
      run += v;
    }
    deg[n] = (int)run;
    dinv[n] = (run > 0) ? rsqrtf((float)run) : 0.0f;
    rdeg[n] = sqrtf((float)run);
  }
  red[t] = (int)run;
  __syncthreads();
  for (int d=128; d>0; d>>=1){
    if (t < d) red[t] += red[t+d];
    __syncthreads();
  }
  if (t == 0) chunkSum[blockIdx.x] = red[0];
}

// off-scan with the chunk-level scan folded in (every block redundantly scans 196 chunk sums).
__global__ __launch_bounds__(256) void scan3_kernel(const int* __restrict__ deg, const int* __restrict__ chunkSum,
                                                    int* __restrict__ off){
  __shared__ int part[256];
  __shared__ int cbase[256];
  int t = threadIdx.x;
  int cv = (t < NCHUNK) ? chunkSum[t] : 0;
  cbase[t] = cv;
  __syncthreads();
  for (int d=1; d<256; d<<=1){
    int x = (t>=d) ? cbase[t-d] : 0;
    __syncthreads();
    cbase[t] += x;
    __syncthreads();
  }
  int base = (blockIdx.x > 0) ? cbase[blockIdx.x-1] : 0;
  if (blockIdx.x == 0 && t == 0) off[N_NODES] = cbase[NCHUNK-1];
  int i = blockIdx.x*256 + t;
  int v = (i < N_NODES) ? deg[i] : 0;
  part[t] = v;
  __syncthreads();
  for (int d=1; d<256; d<<=1){
    int x = (t>=d) ? part[t-d] : 0;
    __syncthreads();
    part[t] += x;
    __syncthreads();
  }
  if (i < N_NODES) off[i] = base + part[t] - v;
}

// ---------------- CSR fill: LDS cursors, exact per-(block,segment) bases, no global atomics ----------------

__global__ __launch_bounds__(1024) void fillB_kernel(const int* __restrict__ row, const int* __restrict__ col,
                                                     const int* __restrict__ off, const ushort* __restrict__ C,
                                                     ushort* __restrict__ csrS){
  __shared__ uint cur[NBL];
  const int nb = blockIdx.x, s = blockIdx.y;
  const uint n0 = nb*NBL;
  const int t = threadIdx.x;
  #pragma unroll
  for (int k=0;k<NBL/1024;k++){
    int idx = k*1024 + t;
    int n = (int)n0 + idx;
    cur[idx] = (n < N_NODES) ? (uint)off[n] + C[(size_t)s*NPAD + n] : 0u;
  }
  __syncthreads();
  const uint4* cvv = (const uint4*)col;
  const uint4* rvv = (const uint4*)row;
  const int cb = s*CHUNKS_PER_SEG, ce = cb + CHUNKS_PER_SEG;
  for (int c = cb + t; c < ce; c += 1024){
    uint4 cv4 = cvv[c];
    uint4 rv4 = rvv[c];
    unsigned d0 = cv4.x - n0, d1 = cv4.y - n0, d2 = cv4.z - n0, d3 = cv4.w - n0;
    if (d0 < NBL){ uint p = atomicAdd(&cur[d0], 1u); csrS[p] = (ushort)rv4.x; }
    if (d1 < NBL){ uint p = atomicAdd(&cur[d1], 1u); csrS[p] = (ushort)rv4.y; }
    if (d2 < NBL){ uint p = atomicAdd(&cur[d2], 1u); csrS[p] = (ushort)rv4.z; }
    if (d3 < NBL){ uint p = atomicAdd(&cur[d3], 1u); csrS[p] = (ushort)rv4.w; }
  }
}

// ---------------- fp32 -> f16 conversions ----------------

__global__ __launch_bounds__(256) void cvt_x_kernel(const float* __restrict__ x, const float* __restrict__ dinv,
                                                    ushort* __restrict__ x16, ushort* __restrict__ xs16){
  int i = blockIdx.x*256 + threadIdx.x;   // 800000 chunks of 8 f16
  int node = i >> 4;
  float di = dinv[node];
  const float4* xin = (const float4*)x;
  float4 a = xin[(size_t)i*2], b = xin[(size_t)i*2+1];
  HU o, os;
  o.h[0]=(_Float16)a.x; o.h[1]=(_Float16)a.y; o.h[2]=(_Float16)a.z; o.h[3]=(_Float16)a.w;
  o.h[4]=(_Float16)b.x; o.h[5]=(_Float16)b.y; o.h[6]=(_Float16)b.z; o.h[7]=(_Float16)b.w;
  os.h[0]=(_Float16)(di*a.x); os.h[1]=(_Float16)(di*a.y); os.h[2]=(_Float16)(di*a.z); os.h[3]=(_Float16)(di*a.w);
  os.h[4]=(_Float16)(di*b.x); os.h[5]=(_Float16)(di*b.y); os.h[6]=(_Float16)(di*b.z); os.h[7]=(_Float16)(di*b.w);
  ((uint4*)x16)[i]  = o.u;
  ((uint4*)xs16)[i] = os.u;
}

__global__ __launch_bounds__(256) void cvt_w_kernel(const float* __restrict__ W1, const float* __restrict__ W2,
                                                    const float* __restrict__ W3, const float* __restrict__ Wf,
                                                    ushort* __restrict__ Wt){
  int m = blockIdx.x >> 2, q = blockIdx.x & 3;
  const float* src = (m < 4) ? (W1 + (size_t)m*16384)
                   : (m < 8) ? (W2 + (size_t)(m-4)*16384)
                   : (m < 12)? (W3 + (size_t)(m-8)*16384)
                   : Wf;
  ushort* dst = Wt + (size_t)m*16384;
  for (int it = threadIdx.x; it < 1024; it += 256){
    int idx = q*1024 + it;
    int n  = idx >> 5;
    int k4 = (idx & 31)*4;
    float v0 = src[(size_t)(k4+0)*D + n];
    float v1 = src[(size_t)(k4+1)*D + n];
    float v2 = src[(size_t)(k4+2)*D + n];
    float v3 = src[(size_t)(k4+3)*D + n];
    union { uint2 u; _Float16 h[4]; } o;
    o.h[0]=(_Float16)v0; o.h[1]=(_Float16)v1; o.h[2]=(_Float16)v2; o.h[3]=(_Float16)v3;
    *(uint2*)(dst + (size_t)n*D + k4) = o.u;
  }
}

// ---------------- SpMM, full-row gather, s-form output only ----------------

__global__ __launch_bounds__(256) void spmm16_kernel(const ushort* __restrict__ sIn, ushort* __restrict__ sOut,
                                                     const int* __restrict__ off, const ushort* __restrict__ csrS,
                                                     const float* __restrict__ dinv){
  int g = blockIdx.x*256 + threadIdx.x;
  int node = g >> 4;
  if (node >= N_NODES) return;
  int c8 = (g & 15)*8;
  int b = off[node], e = off[node+1];
  float acc[8];
  #pragma unroll
  for (int k=0;k<8;k++) acc[k] = 0.f;
  int i = b;
  for (; i+16 <= e; i += 16){
    HU v[16];
    #pragma unroll
    for (int u=0;u<16;u++){
      int s = csrS[i+u];
      v[u].u = *(const uint4*)(sIn + (size_t)s*D + c8);
    }
    #pragma unroll
    for (int u=0;u<16;u++){
      #pragma unroll
      for (int k=0;k<8;k++) acc[k] += (float)v[u].h[k];
    }
  }
  for (; i+4 <= e; i += 4){
    HU v[4];
    #pragma unroll
    for (int u=0;u<4;u++){
      int s = csrS[i+u];
      v[u].u = *(const uint4*)(sIn + (size_t)s*D + c8);
    }
    #pragma unroll
    for (int u=0;u<4;u++){
      #pragma unroll
      for (int k=0;k<8;k++) acc[k] += (float)v[u].h[k];
    }
  }
  for (; i < e; i++){
    int s = csrS[i];
    HU v0; v0.u = *(const uint4*)(sIn + (size_t)s*D + c8);
    #pragma unroll
    for (int k=0;k<8;k++) acc[k] += (float)v0.h[k];
  }
  float d2 = dinv[node]*dinv[node];
  HU os;
  #pragma unroll
  for (int k=0;k<8;k++) os.h[k] = (_Float16)(d2*acc[k]);
  __builtin_nontemporal_store(os.v, (u32x4*)(sOut + (size_t)node*D + c8));
}

// ---------------- layer GEMM: col-split (grid 782x2), double-buffered staging ----------------
// out = relu( h0 @ W0 + sum_{k=1..3} (s_k*sqrt(deg)) @ W_k + b ); writes Ah (h) + As (dinv.*h).
// Block = 64 rows x 64 cols; 4 waves, wave (wm,wn) = 32x32 (2x2 16x16 frags).
// Staging double-buffered: src k+1 global loads issued before src k MFMAs; NO in/out aliasing.

__global__ __launch_bounds__(256) void gemm_layer_kernel(const ushort* __restrict__ s0,
    const ushort* __restrict__ s1, const ushort* __restrict__ s2, const ushort* __restrict__ s3,
    const ushort* __restrict__ Wt, const float* __restrict__ bias,
    const float* __restrict__ rdeg, const float* __restrict__ dinv,
    ushort* __restrict__ Ah, ushort* __restrict__ As){
  __shared__ ushort Xs[2][64*136];
  const int tid  = threadIdx.x;
  const int wave = tid >> 6, lane = tid & 63;
  const int quad = lane >> 4, l16 = lane & 15;
  const int wm = wave & 1, wn = wave >> 1;
  const int row0 = blockIdx.x * 64;
  const int cb   = blockIdx.y * 64;
  const int rbase = tid >> 4, cc = tid & 15;
  const ushort* srcs[4] = {s0, s1, s2, s3};

  float rd[4];
  #pragma unroll
  for (int p=0;p<4;p++){
    int gr = row0 + rbase + 16*p;
    rd[p] = (gr < N_NODES) ? rdeg[gr] : 0.f;
  }

  f32x4 acc[2][2];
  #pragma unroll
  for (int i=0;i<2;i++)
    #pragma unroll
    for (int j=0;j<2;j++) acc[i][j] = (f32x4){0.f,0.f,0.f,0.f};

  // prefetch src0 (h-form, no scale)
  #pragma unroll
  for (int p=0;p<4;p++){
    int r = rbase + 16*p, gr = row0 + r;
    HU v; v.u = make_uint4(0u,0u,0u,0u);
    if (gr < N_NODES) v.u = *(const uint4*)(s0 + (size_t)gr*D + cc*8);
    *(uint4*)(&Xs[0][r*136 + cc*8]) = v.u;
  }
  __syncthreads();

  #pragma unroll
  for (int src=0; src<4; src++){
    const int cur = src & 1;
    HU pv[4];
    if (src < 3){
      const ushort* sp = srcs[src+1];
      #pragma unroll
      for (int p=0;p<4;p++){
        int r = rbase + 16*p, gr = row0 + r;
        pv[p].u = make_uint4(0u,0u,0u,0u);
        if (gr < N_NODES) pv[p].u = *(const uint4*)(sp + (size_t)gr*D + cc*8);
      }
    }
    const ushort* wsrc = Wt + (size_t)src*16384;
    #pragma unroll
    for (int ks=0; ks<4; ks++){
      f16x8 a0 = *(const f16x8*)(&Xs[cur][(wm*32 +      l16)*136 + ks*32 + quad*8]);
      f16x8 a1 = *(const f16x8*)(&Xs[cur][(wm*32 + 16 + l16)*136 + ks*32 + quad*8]);
      #pragma unroll
      for (int j=0;j<2;j++){
        f16x8 bfrag = *(const f16x8*)(wsrc + (size_t)(cb + wn*32 + j*16 + l16)*D + ks*32 + quad*8);
        acc[0][j] = __builtin_amdgcn_mfma_f32_16x16x32_f16(a0, bfrag, acc[0][j], 0, 0, 0);
        acc[1][j] = __builtin_amdgcn_mfma_f32_16x16x32_f16(a1, bfrag, acc[1][j], 0, 0, 0);
      }
    }
    if (src < 3){
      #pragma unroll
      for (int p=0;p<4;p++){
        int r = rbase + 16*p;
        #pragma unroll
        for (int k=0;k<8;k++) pv[p].h[k] = (_Float16)((float)pv[p].h[k]*rd[p]);  // s-form -> h-form
        *(uint4*)(&Xs[cur^1][r*136 + cc*8]) = pv[p].u;
      }
    }
    __syncthreads();
  }

  #pragma unroll
  for (int j=0;j<2;j++){
    int colj = cb + wn*32 + j*16 + l16;
    float bv = bias[colj];
    #pragma unroll
    for (int i=0;i<2;i++){
      int brow = row0 + wm*32 + i*16 + quad*4;
      #pragma unroll
      for (int r=0;r<4;r++){
        int grow = brow + r;
        if (grow < N_NODES){
          float v = fmaxf(acc[i][j][r] + bv, 0.f);
          Ah[(size_t)grow*D + colj] = __builtin_bit_cast(ushort, (_Float16)v);
          As[(size_t)grow*D + colj] = __builtin_bit_cast(ushort, (_Float16)(dinv[grow]*v));
        }
      }
    }
  }
}

// ---------------- layer-3 GEMM + fused head (full width, double-buffered staging, fp32 out) ----------------

__global__ __launch_bounds__(256) void gemm_head_kernel(const ushort* __restrict__ s0,
    const ushort* __restrict__ s1, const ushort* __restrict__ s2, const ushort* __restrict__ s3,
    const ushort* __restrict__ Wt, const float* __restrict__ bias,
    const ushort* __restrict__ WtH, const float* __restrict__ biasH,
    const float* __restrict__ rdeg, float* __restrict__ outF){
  __shared__ ushort Xs[2][64*136];
  const int tid  = threadIdx.x;
  const int wave = tid >> 6, lane = tid & 63;
  const int quad = lane >> 4, l16 = lane & 15;
  const int wm = wave & 1, wn = wave >> 1;
  const int row0 = blockIdx.x * 64;
  const int rbase = tid >> 4, cc = tid & 15;
  const ushort* srcs[4] = {s0, s1, s2, s3};

  float rd[4];
  #pragma unroll
  for (int p=0;p<4;p++){
    int gr = row0 + rbase + 16*p;
    rd[p] = (gr < N_NODES) ? rdeg[gr] : 0.f;
  }

  f32x4 acc[2][4];
  #pragma unroll
  for (int i=0;i<2;i++)
    #pragma unroll
    for (int j=0;j<4;j++) acc[i][j] = (f32x4){0.f,0.f,0.f,0.f};

  #pragma unroll
  for (int p=0;p<4;p++){
    int r = rbase + 16*p, gr = row0 + r;
    HU v; v.u = make_uint4(0u,0u,0u,0u);
    if (gr < N_NODES) v.u = *(const uint4*)(s0 + (size_t)gr*D + cc*8);
    *(uint4*)(&Xs[0][r*136 + cc*8]) = v.u;
  }
  __syncthreads();

  #pragma unroll
  for (int src=0; src<4; src++){
    const int cur = src & 1;
    HU pv[4];
    if (src < 3){
      const ushort* sp = srcs[src+1];
      #pragma unroll
      for (int p=0;p<4;p++){
        int r = rbase + 16*p, gr = row0 + r;
        pv[p].u = make_uint4(0u,0u,0u,0u);
        if (gr < N_NODES) pv[p].u = *(const uint4*)(sp + (size_t)gr*D + cc*8);
      }
    }
    const ushort* wsrc = Wt + (size_t)src*16384;
    #pragma unroll
    for (int ks=0; ks<4; ks++){
      f16x8 a0 = *(const f16x8*)(&Xs[cur][(wm*32 +      l16)*136 + ks*32 + quad*8]);
      f16x8 a1 = *(const f16x8*)(&Xs[cur][(wm*32 + 16 + l16)*136 + ks*32 + quad*8]);
      #pragma unroll
      for (int j=0;j<4;j++){
        f16x8 bfrag = *(const f16x8*)(wsrc + (size_t)(wn*64 + j*16 + l16)*D + ks*32 + quad*8);
        acc[0][j] = __builtin_amdgcn_mfma_f32_16x16x32_f16(a0, bfrag, acc[0][j], 0, 0, 0);
        acc[1][j] = __builtin_amdgcn_mfma_f32_16x16x32_f16(a1, bfrag, acc[1][j], 0, 0, 0);
      }
    }
    if (src < 3){
      #pragma unroll
      for (int p=0;p<4;p++){
        int r = rbase + 16*p;
        #pragma unroll
        for (int k=0;k<8;k++) pv[p].h[k] = (_Float16)((float)pv[p].h[k]*rd[p]);
        *(uint4*)(&Xs[cur^1][r*136 + cc*8]) = pv[p].u;
      }
    }
    __syncthreads();
  }

  // layer-3 h-tile (bias+relu, f16) -> Xs[0] (last read in src=2 iter; synced since)
  #pragma unroll
  for (int j=0;j<4;j++){
    int colj = wn*64 + j*16 + l16;
    float bv = bias[colj];
    #pragma unroll
    for (int i=0;i<2;i++){
      int lrow = wm*32 + i*16 + quad*4;
      #pragma unroll
      for (int r=0;r<4;r++){
        float v = fmaxf(acc[i][j][r] + bv, 0.f);
        Xs[0][(lrow + r)*136 + colj] = __builtin_bit_cast(ushort, (_Float16)v);
      }
    }
  }
  __syncthreads();
  f32x4 acc2[2][4];
  #pragma unroll
  for (int i=0;i<2;i++)
    #pragma unroll
    for (int j=0;j<4;j++) acc2[i][j] = (f32x4){0.f,0.f,0.f,0.f};
  #pragma unroll
  for (int ks=0; ks<4; ks++){
    f16x8 a0 = *(const f16x8*)(&Xs[0][(wm*32 +      l16)*136 + ks*32 + quad*8]);
    f16x8 a1 = *(const f16x8*)(&Xs[0][(wm*32 + 16 + l16)*136 + ks*32 + quad*8]);
    #pragma unroll
    for (int j=0;j<4;j++){
      f16x8 bfrag = *(const f16x8*)(WtH + (size_t)(wn*64 + j*16 + l16)*D + ks*32 + quad*8);
      acc2[0][j] = __builtin_amdgcn_mfma_f32_16x16x32_f16(a0, bfrag, acc2[0][j], 0, 0, 0);
      acc2[1][j] = __builtin_amdgcn_mfma_f32_16x16x32_f16(a1, bfrag, acc2[1][j], 0, 0, 0);
    }
  }
  #pragma unroll
  for (int j=0;j<4;j++){
    int colj = wn*64 + j*16 + l16;
    float bv = biasH[colj];
    #pragma unroll
    for (int i=0;i<2;i++){
      int brow = row0 + wm*32 + i*16 + quad*4;
      #pragma unroll
      for (int r=0;r<4;r++){
        int grow = brow + r;
        if (grow < N_NODES)
          outF[(size_t)grow*D + colj] = acc2[i][j][r] + bv;
      }
    }
  }
}

// ---------------- launch ----------------

extern "C" void kernel_launch(void* const* d_in, const int* in_sizes, int n_in,
                              void* d_out, int out_size, void* d_ws, size_t ws_size,
                              hipStream_t stream){
  const float* x  = (const float*)d_in[0];
  const int*   ei = (const int*)d_in[1];
  const float* W1 = (const float*)d_in[2];
  const float* b1 = (const float*)d_in[3];
  const float* W2 = (const float*)d_in[4];
  const float* b2 = (const float*)d_in[5];
  const float* W3 = (const float*)d_in[6];
  const float* b3 = (const float*)d_in[7];
  const float* Wf = (const float*)d_in[8];
  const float* bf = (const float*)d_in[9];
  float* out = (float*)d_out;

  const int* row = ei;            // edge_index[0]
  const int* col = ei + N_EDGES;  // edge_index[1]

  // workspace layout (~95 MB)
  char* w = (char*)d_ws;
  ushort* csrS = (ushort*)w;  w += (size_t)N_EDGES*2;
  ushort* x16  = (ushort*)w;  w += (size_t)N_NODES*D*2;
  ushort* xs16 = (ushort*)w;  w += (size_t)N_NODES*D*2;    // reused as Ds (hop-3 s) after hop-1 (dead then)
  ushort* Ah   = (ushort*)w;  w += (size_t)N_NODES*D*2;
  ushort* As   = (ushort*)w;  w += (size_t)N_NODES*D*2;
  ushort* Ah2  = (ushort*)w;  w += (size_t)N_NODES*D*2;    // ping-pong (col-split gemm cannot alias in/out)
  ushort* Bs   = (ushort*)w;  w += (size_t)N_NODES*D*2;
  ushort* Cs   = (ushort*)w;  w += (size_t)N_NODES*D*2;
  ushort* Wt   = (ushort*)w;  w += (size_t)13*D*D*2;
  int* deg     = (int*)w;     w += (size_t)N_NODES*4;
  int* off     = (int*)w;     w += (size_t)(N_NODES+1)*4;
  int* chunkS  = (int*)w;     w += (size_t)256*4;
  float* dinv  = (float*)w;   w += (size_t)N_NODES*4;
  float* rdeg  = (float*)w;
  ushort* Ds = xs16;
  // Cc (16.8 MB = NSEG x NPAD ushort) aliases Ah+As: dead before gemm L1 writes Ah/As.
  ushort* Cc = Ah;

  const int GB = (N_NODES + 63)/64;   // 782
  const int SB = N_NODES*16/256;      // 3125 (exact)

  histA_kernel<<<dim3(NODEBLKS,NSEG),1024,0,stream>>>(col, Cc);
  segprefix_kernel<<<NCHUNK,256,0,stream>>>(Cc, deg, dinv, rdeg, chunkS);
  scan3_kernel<<<NCHUNK,256,0,stream>>>(deg, chunkS, off);
  fillB_kernel<<<dim3(NODEBLKS,NSEG),1024,0,stream>>>(row, col, off, Cc, csrS);
  cvt_x_kernel<<<3125,256,0,stream>>>(x, dinv, x16, xs16);
  cvt_w_kernel<<<52,256,0,stream>>>(W1, W2, W3, Wf, Wt);

  // layer 1
  spmm16_kernel<<<SB,256,0,stream>>>(xs16, Bs, off, csrS, dinv);
  spmm16_kernel<<<SB,256,0,stream>>>(Bs,   Cs, off, csrS, dinv);
  spmm16_kernel<<<SB,256,0,stream>>>(Cs,   Ds, off, csrS, dinv);
  gemm_layer_kernel<<<dim3(GB,2),256,0,stream>>>(x16, Bs, Cs, Ds, Wt+0*16384, b1, rdeg, dinv, Ah, As);
  // layer 2 (in Ah, out Ah2 — ping-pong, no aliasing)
  spmm16_kernel<<<SB,256,0,stream>>>(As, Bs, off, csrS, dinv);
  spmm16_kernel<<<SB,256,0,stream>>>(Bs, Cs, off, csrS, dinv);
  spmm16_kernel<<<SB,256,0,stream>>>(Cs, Ds, off, csrS, dinv);
  gemm_layer_kernel<<<dim3(GB,2),256,0,stream>>>(Ah, Bs, Cs, Ds, Wt+4*16384, b2, rdeg, dinv, Ah2, As);
  // layer 3 + fused head (fp32 out)
  spmm16_kernel<<<SB,256,0,stream>>>(As, Bs, off, csrS, dinv);
  spmm16_kernel<<<SB,256,0,stream>>>(Bs, Cs, off, csrS, dinv);
  spmm16_kernel<<<SB,256,0,stream>>>(Cs, Ds, off, csrS, dinv);
  gemm_head_kernel<<<GB,256,0,stream>>>(Ah2, Bs, Cs, Ds, Wt+8*16384, b3, Wt+12*16384, bf, rdeg, out);
}